// Round 13
// baseline (209.607 us; speedup 1.0000x reference)
//
#include <hip/hip_runtime.h>
#include <hip/hip_bf16.h>
#include <cstdint>
#include <cstddef>

// Problem constants
#define BB 4
#define LL 4096
#define HH 16
#define M1 16384      // B*L
#define E3 3072
#define EE 1024
#define ANGC 3.8349519697141029e-4f   // (pi/2)/4096
#define EPSC 1e-4f

typedef __attribute__((ext_vector_type(8))) short bf16x8;
typedef __attribute__((ext_vector_type(4))) float f32x4;
typedef __attribute__((ext_vector_type(8))) unsigned short us8;

static __device__ __forceinline__ float bf2f(unsigned short u) {
  union { unsigned int i; float f; } a; a.i = ((unsigned int)u) << 16; return a.f;
}
static __device__ __forceinline__ unsigned short f2bf(float x) {
  union { float f; unsigned int i; } a; a.f = x;
  unsigned int r = a.i + 0x7FFFu + ((a.i >> 16) & 1u);  // RNE
  return (unsigned short)(r >> 16);
}
static __device__ __forceinline__ void gload16(const void* g, void* l) {
  __builtin_amdgcn_global_load_lds((const __attribute__((address_space(1))) void*)g,
                                   (__attribute__((address_space(3))) void*)l, 16, 0, 0);
}

#define BAR()   asm volatile("s_barrier" ::: "memory")
#define LGKM0() asm volatile("s_waitcnt lgkmcnt(0)" ::: "memory")
#define VMC4()  asm volatile("s_waitcnt vmcnt(4)" ::: "memory")
#define VMC0()  asm volatile("s_waitcnt vmcnt(0)" ::: "memory")
#define PRIO1() __builtin_amdgcn_s_setprio(1)
#define PRIO0() __builtin_amdgcn_s_setprio(0)

// ---------------- fused prep: x f32->bf16 cvt + W transposes + kvb/ksum zero ----------------
static __device__ __forceinline__ void transpose_body(const float* __restrict__ src,
                                                      unsigned short* __restrict__ dst,
                                                      int R, int C, int bx, int by,
                                                      float (*tile)[33]) {
  int c0 = bx * 32, r0 = by * 32;
  int tx = threadIdx.x & 31, ty = threadIdx.x >> 5;
#pragma unroll
  for (int k = 0; k < 4; ++k)
    tile[ty + 8*k][tx] = src[(size_t)(r0 + ty + 8*k) * C + c0 + tx];
  __syncthreads();
#pragma unroll
  for (int k = 0; k < 4; ++k)
    dst[(size_t)(c0 + ty + 8*k) * R + r0 + tx] = f2bf(tile[tx][ty + 8*k]);
}

__global__ __launch_bounds__(256) void k_prep(const float* __restrict__ x,
                                              const float* __restrict__ Wq,
                                              const float* __restrict__ Wo,
                                              unsigned short* __restrict__ xb,
                                              unsigned short* __restrict__ WqT,
                                              unsigned short* __restrict__ WoT,
                                              float* __restrict__ zbase) {
  __shared__ float tile[32][33];
  const int bid = blockIdx.x;
  if (bid < 8192) {                       // cvt x: 8192*256 = 2097152 us8-chunks
    int i = bid * 256 + threadIdx.x;
    const float4* s = (const float4*)x + (size_t)i * 2;
    float4 a = s[0], b = s[1];
    us8 o;
    o[0]=f2bf(a.x); o[1]=f2bf(a.y); o[2]=f2bf(a.z); o[3]=f2bf(a.w);
    o[4]=f2bf(b.x); o[5]=f2bf(b.y); o[6]=f2bf(b.z); o[7]=f2bf(b.w);
    *(us8*)(xb + (size_t)i * 8) = o;
  } else if (bid < 8192 + 3072) {         // W_qkv transpose: 96 x 32 blocks
    int r = bid - 8192;
    transpose_body(Wq, WqT, 1024, 3072, r % 96, r / 96, tile);
  } else if (bid < 11264 + 1024) {        // W_out transpose: 32 x 32 blocks
    int r = bid - 11264;
    transpose_body(Wo, WoT, 1024, 1024, r % 32, r / 32, tile);
  } else {                                // zero kvb+ksum: 520 blocks x 4096B
    int r = bid - 12288;
    float4 z = {0.f, 0.f, 0.f, 0.f};
    *(float4*)((char*)zbase + (size_t)r * 4096 + threadIdx.x * 16) = z;
  }
}

// ============ 256x256 bf16 MFMA GEMM — m201-style double-barrier phases (R13) ============
// C[M,N] = A[M,K] @ Bt[N,K]^T + bias.  MODE 0: bf16 out + relu cols<2048. MODE 1: f32 out.
// 512 thr = 8 waves (2M x 4N); per-wave 128x64 out = acc[8][4]; BK=64; LDS 128KB (2 bufs).
// LDS tile [256 rows][8 chunks of 16B], chunk-slot swizzle slot = ck ^ (row&7), applied
// BOTH sides (inverse-swizzled global source, swizzled ds_read).  K-loop conflict-free.
// R13 phase (m201 template): [ds_reads ; 1 half-tile stage ; BAR ; lgkmcnt(0) ;
// setprio(1) ; 16 MFMA ; setprio(0) ; (vmcnt gate at ph3/ph7) ; BAR].
// Mechanism: reads issue before the leading barrier; the barrier's wave-stagger wait
// absorbs LDS latency; lgkmcnt(0) is ~free after it; the MFMA cluster then runs with
// ZERO internal lgkm stalls (single-barrier variants let the compiler interleave
// lgkmcnt waits inside the cluster -> MFMA pipe serialized with LDS returns, the
// 42%-MfmaUtil plateau of R5-R12).  Trailing barrier keeps phases aligned.
// Stage order per iter (t0=2i buf0 ph0-3, t1=2i+1 buf1 ph4-7), 1 half/phase:
//   ph0:t1.A0  ph1:t1.A1  ph2:t2.B0  ph3:t2.B1 [VMC4 gate; VMC0 last iter]
//   ph4:t2.A0  ph5:t2.A1  ph6:t3.B0  ph7:t3.B1 [VMC4 gate]
// WAR proofs unchanged from R5 (trailing barriers only ADD sync).

static __device__ __forceinline__ bf16x8 rdfrag(const char* base, int row, int ck) {
  return *(const bf16x8*)(base + row * 128 + (((ck) ^ ((row) & 7)) << 4));
}

static __device__ __forceinline__ void stage2h(const unsigned short* __restrict__ base,
                                               size_t off, size_t rowK64, char* ldst) {
  gload16(base + off, ldst);
  gload16(base + off + rowK64, ldst + 8192);
}

#define PH_FIRST(AbP, BbP, AR)                                                  \
  do {                                                                          \
    _Pragma("unroll")                                                           \
    for (int n = 0; n < 4; ++n) {                                               \
      const int br = wc * 64 + n * 16 + lr;                                     \
      bF[n][0] = rdfrag((BbP), br, lg);                                         \
      bF[n][1] = rdfrag((BbP), br, 4 + lg);                                     \
    }                                                                           \
    AR[0][0] = rdfrag((AbP), wr * 128 + lr, lg);                                \
    AR[0][1] = rdfrag((AbP), wr * 128 + lr, 4 + lg);                            \
    AR[1][0] = rdfrag((AbP), wr * 128 + 16 + lr, lg);                           \
    AR[1][1] = rdfrag((AbP), wr * 128 + 16 + lr, 4 + lg);                       \
  } while (0)

#define PH_A(AbP, mb, AR)                                                       \
  do {                                                                          \
    AR[0][0] = rdfrag((AbP), wr * 128 + (mb) * 16 + lr, lg);                    \
    AR[0][1] = rdfrag((AbP), wr * 128 + (mb) * 16 + lr, 4 + lg);                \
    AR[1][0] = rdfrag((AbP), wr * 128 + (mb) * 16 + 16 + lr, lg);               \
    AR[1][1] = rdfrag((AbP), wr * 128 + (mb) * 16 + 16 + lr, 4 + lg);           \
  } while (0)

#define MMA16(mb, AR)                                                           \
  do {                                                                          \
    _Pragma("unroll")                                                           \
    for (int kk = 0; kk < 2; ++kk) {                                            \
      _Pragma("unroll")                                                         \
      for (int n = 0; n < 4; ++n) {                                             \
        acc[(mb)][n] = __builtin_amdgcn_mfma_f32_16x16x32_bf16(                 \
            AR[0][kk], bF[n][kk], acc[(mb)][n], 0, 0, 0);                       \
        acc[(mb) + 1][n] = __builtin_amdgcn_mfma_f32_16x16x32_bf16(             \
            AR[1][kk], bF[n][kk], acc[(mb) + 1][n], 0, 0, 0);                   \
      }                                                                         \
    }                                                                           \
  } while (0)

template<int MODE>
__global__ __launch_bounds__(512, 2) void k_gemm256(const unsigned short* __restrict__ A,
                                                    const unsigned short* __restrict__ Bt,
                                                    const float* __restrict__ bias,
                                                    void* __restrict__ Cout,
                                                    int N, int K) {
  __shared__ __align__(16) unsigned short lds[4][16384];  // [buf*2 + (0=A,1=B)][256 rows * 64]
  const int tid = threadIdx.x;
  const int wid = tid >> 6, lane = tid & 63;
  const int lr = lane & 15, lg = lane >> 4;
  const int wr = wid >> 2, wc = wid & 3;

  // L2 mapping (R4/R12-proven neutral-or-better): per-XCD 4x4 tile rectangles.
  const int nx = gridDim.x;
  const int rawbid = blockIdx.y * nx + blockIdx.x;
  const int xcd = rawbid & 7, s = rawbid >> 3;
  const int g = s >> 4, r = s & 15;
  const int bm = (xcd * 8 + ((g & 1) << 2) + (r & 3)) * 256;
  const int bn = ((g >> 1) * 4 + (r >> 2)) * 256;

  char* LA0 = (char*)&lds[0][0];
  char* LB0 = (char*)&lds[1][0];
  char* LA1 = (char*)&lds[2][0];
  char* LB1 = (char*)&lds[3][0];

  f32x4 acc[8][4] = {};
  bf16x8 bF[4][2], aF[2][2], aG[2][2];

  // staging: thread covers rows {h*128+rr, +64}, stored chunk cc, src chunk cc^(rr&7)
  const int rr = tid >> 3, cc = tid & 7;
  const size_t rowK64 = (size_t)64 * K, rowK128 = (size_t)128 * K;
  const size_t aoff = (size_t)(bm + rr) * K + ((cc ^ (rr & 7)) << 3);
  const size_t boff = (size_t)(bn + rr) * K + ((cc ^ (rr & 7)) << 3);

#define STAGE_A(h, kt, L) stage2h(A,  aoff + (h) * rowK128 + (kt), rowK64, (L) + (h) * 16384 + tid * 16)
#define STAGE_B(h, kt, L) stage2h(Bt, boff + (h) * rowK128 + (kt), rowK64, (L) + (h) * 16384 + tid * 16)

  const int NT = K >> 6, NI = NT >> 1;

  // prologue: T0 full (buf0) + T1.B (buf1); VMC4 retires T0 (8 loads), leaves T1.B (4)
  STAGE_A(0, 0, LA0); STAGE_A(1, 0, LA0);
  STAGE_B(0, 0, LB0); STAGE_B(1, 0, LB0);
  STAGE_B(0, 64, LB1); STAGE_B(1, 64, LB1);
  VMC4();
  BAR();

  for (int it = 0; it < NI; ++it) {
    const int kt1 = (2*it + 1) << 6;
    const int kt2 = (2*it + 2) << 6;
    const int kt3 = (2*it + 3) << 6;
    const bool s2 = kt2 < K, s3 = kt3 < K;

    // ---------- tile t0 : buf0 ----------
    PH_FIRST(LA0, LB0, aF);                 // 12 ds_read_b128
    STAGE_A(0, kt1, LA1);
    BAR(); LGKM0();
    PRIO1(); MMA16(0, aF); PRIO0();
    BAR();

    PH_A(LA0, 2, aG);
    STAGE_A(1, kt1, LA1);
    BAR(); LGKM0();
    PRIO1(); MMA16(2, aG); PRIO0();
    BAR();

    PH_A(LA0, 4, aF);
    if (s2) STAGE_B(0, kt2, LB0);           // LB0 free: reg-captured in ph0
    BAR(); LGKM0();
    PRIO1(); MMA16(4, aF); PRIO0();
    BAR();

    PH_A(LA0, 6, aG);
    if (s2) STAGE_B(1, kt2, LB0);
    BAR(); LGKM0();
    PRIO1(); MMA16(6, aG); PRIO0();
    if (it == NI - 1) { VMC0(); } else { VMC4(); }   // gate: t1 fully landed
    BAR();

    // ---------- tile t1 : buf1 ----------
    PH_FIRST(LA1, LB1, aF);
    if (s2) STAGE_A(0, kt2, LA0);
    BAR(); LGKM0();
    PRIO1(); MMA16(0, aF); PRIO0();
    BAR();

    PH_A(LA1, 2, aG);
    if (s2) STAGE_A(1, kt2, LA0);
    BAR(); LGKM0();
    PRIO1(); MMA16(2, aG); PRIO0();
    BAR();

    PH_A(LA1, 4, aF);
    if (s3) STAGE_B(0, kt3, LB1);           // LB1 free: reg-captured in ph4
    BAR(); LGKM0();
    PRIO1(); MMA16(4, aF); PRIO0();
    BAR();

    PH_A(LA1, 6, aG);
    if (s3) STAGE_B(1, kt3, LB1);
    BAR(); LGKM0();
    PRIO1(); MMA16(6, aG); PRIO0();
    VMC4();                                 // gate: t2 fully landed
    BAR();
  }
#undef STAGE_A
#undef STAGE_B

  // ---------- epilogue: per-wave LDS strip transpose, coalesced stores ----------
  {
    float* strip = (float*)((char*)&lds[0][0] + wid * 16384);  // 16KB per wave, [16][68] f32
    float bias_v[4]; bool relu_v[4];
#pragma unroll
    for (int n = 0; n < 4; ++n) {
      int col = bn + wc*64 + n*16 + lr;
      bias_v[n] = bias[col];
      relu_v[n] = (MODE == 0) && (col < 2048);
    }
#pragma unroll
    for (int m = 0; m < 8; ++m) {
#pragma unroll
      for (int n = 0; n < 4; ++n)
#pragma unroll
        for (int j = 0; j < 4; ++j) {
          float v = acc[m][n][j] + bias_v[n];
          if (relu_v[n]) v = fmaxf(v, 0.0f);
          strip[(lg*4 + j)*68 + n*16 + lr] = v;
        }
      // wave-local RAW/WAR through LDS: compiler inserts lgkmcnt waits
#pragma unroll
      for (int itr = 0; itr < 4; ++itr) {
        int ch = itr*64 + lane;
        int row = ch >> 4, cg = ch & 15;
        float4 v = *(const float4*)(strip + row*68 + cg*4);
        size_t base = (size_t)(bm + wr*128 + m*16 + row) * N + bn + wc*64 + cg*4;
        if (MODE == 0) {
          ushort4 o;
          o.x = f2bf(v.x); o.y = f2bf(v.y); o.z = f2bf(v.z); o.w = f2bf(v.w);
          *(ushort4*)((unsigned short*)Cout + base) = o;
        } else {
          *(float4*)((float*)Cout + base) = v;
        }
      }
    }
  }
}

// ---------------- stage2: per-head KVc^T/KVs^T accumulation + k-sums ----------------
// Coalesced (R7) + low-contention (R9): grid (4, 64) = 256 blocks (1/CU), each block
// covers 1024 l in 16 subchunks of 64. Thread (pr=tid>>3, pc=tid&7) loads rows l0=2pr,
// l0+1 at d-piece pc*8..+7 — 8 lanes cover one row's 128B contiguously. LDS transpose
// via u32 writes. Swizzle S(d) = (d&7)^(d>>3), both sides.
static __device__ __forceinline__ int swz2(int d) { return (d & 7) ^ (d >> 3); }

__global__ __launch_bounds__(256) void k_stage2(const unsigned short* __restrict__ qkv,
                                                float* __restrict__ kvb,
                                                float* __restrict__ ksumb) {
  __shared__ __align__(16) unsigned short kcT[4096];
  __shared__ __align__(16) unsigned short ksT[4096];
  __shared__ __align__(16) unsigned short vT [4096];
  const int tid = threadIdx.x;
  const int head = blockIdx.y;
  const int b = head >> 4, h = head & 15;
  const int lane = tid & 63, wid = tid >> 6;
  const int lr = lane & 15, lg = lane >> 4;
  const int mt = wid >> 1, eh = wid & 1;
  const int pr = tid >> 3;        // l-pair index: l = 2pr, 2pr+1
  const int pc = tid & 7;         // d-piece: d = pc*8 + i

  f32x4 acc[2][4] = {};
  float ksacc = 0.0f;
  const int mtk = tid >> 6, dk = tid & 63;   // ksum role (tid<128)
  const size_t qbase = (size_t)b * LL * E3;

  for (int sc = 0; sc < 16; ++sc) {
    const int lbase = blockIdx.x * 1024 + sc * 64;
    __syncthreads();
    {
      const int l0 = 2 * pr;
      const int p0 = lbase + l0;
      float s0, c0, s1, c1;
      __sincosf((float)p0 * ANGC, &s0, &c0);
      __sincosf((float)(p0 + 1) * ANGC, &s1, &c1);
      const unsigned short* kp = qkv + qbase + (size_t)p0 * E3 + 1024 + h*64 + pc*8;
      us8 kr0 = *(const us8*)kp;
      us8 kr1 = *(const us8*)(kp + E3);
      us8 vr0 = *(const us8*)(kp + 1024);
      us8 vr1 = *(const us8*)(kp + 1024 + E3);
      const int cch = pr >> 2, wb = (pr & 3) * 4;
#pragma unroll
      for (int i = 0; i < 8; ++i) {
        int d = pc*8 + i;
        float ka = bf2f(kr0[i]), kb = bf2f(kr1[i]);
        unsigned int kcp = (unsigned int)f2bf(c0*ka) | ((unsigned int)f2bf(c1*kb) << 16);
        unsigned int ksp = (unsigned int)f2bf(s0*ka) | ((unsigned int)f2bf(s1*kb) << 16);
        unsigned int vp  = (unsigned int)vr0[i] | ((unsigned int)vr1[i] << 16);
        int off = d*128 + ((cch ^ swz2(d)) << 4) + wb;
        *(unsigned int*)((char*)kcT + off) = kcp;
        *(unsigned int*)((char*)ksT + off) = ksp;
        *(unsigned int*)((char*)vT  + off) = vp;
      }
    }
    __syncthreads();
    if (tid < 128) {   // k-sums: row-sum over l of kcT/ksT row dk
      const unsigned short* basep = mtk ? ksT : kcT;
      float sum = 0.0f;
#pragma unroll
      for (int cch2 = 0; cch2 < 8; ++cch2) {
        us8 r2 = *(const us8*)((const char*)basep + dk*128 + ((cch2 ^ swz2(dk)) << 4));
#pragma unroll
        for (int i = 0; i < 8; ++i) sum += bf2f(r2[i]);
      }
      ksacc += sum;
    }
    {
      const unsigned short* kT = mt ? ksT : kcT;
      bf16x8 af[2][2], bf[2][4];
#pragma unroll
      for (int kk = 0; kk < 2; ++kk) {
#pragma unroll
        for (int m = 0; m < 2; ++m) {
          int e = eh*32 + m*16 + lr;
          af[kk][m] = *(const bf16x8*)((const char*)vT + e*128 + ((((kk*4)+lg) ^ swz2(e)) << 4));
        }
#pragma unroll
        for (int n = 0; n < 4; ++n) {
          int d = n*16 + lr;
          bf[kk][n] = *(const bf16x8*)((const char*)kT + d*128 + ((((kk*4)+lg) ^ swz2(d)) << 4));
        }
      }
#pragma unroll
      for (int kk = 0; kk < 2; ++kk)
#pragma unroll
        for (int m = 0; m < 2; ++m)
#pragma unroll
          for (int n = 0; n < 4; ++n)
            acc[m][n] = __builtin_amdgcn_mfma_f32_16x16x32_bf16(af[kk][m], bf[kk][n], acc[m][n], 0, 0, 0);
    }
  }
  float* dst = kvb + (size_t)head * 8192 + mt * 4096;
#pragma unroll
  for (int m = 0; m < 2; ++m)
#pragma unroll
    for (int n = 0; n < 4; ++n)
#pragma unroll
      for (int j = 0; j < 4; ++j) {
        int e = eh*32 + m*16 + lg*4 + j;
        int d = n*16 + lr;
        atomicAdd(&dst[e*64 + d], acc[m][n][j]);
      }
  if (tid < 128) atomicAdd(&ksumb[head*128 + mtk*64 + dk], ksacc);
}

// ---------------- stage3: context + norm + divide -> att bf16 [B*L][E] ----------------
__global__ __launch_bounds__(256) void k_stage3(const unsigned short* __restrict__ qkv,
                                                const float* __restrict__ kvb,
                                                const float* __restrict__ ksumb,
                                                unsigned short* __restrict__ att) {
  __shared__ __align__(16) unsigned short Bl[144 * 64];   // 18KB; reused as strips
  const int tid = threadIdx.x;
  const int head = blockIdx.y;
  const int b = head >> 4, h = head & 15;
  const int l0 = blockIdx.x * 128;
  const int lane = tid & 63, w = tid >> 6;
  const int lr = lane & 15, lg = lane >> 4;

  { // load B into LDS (bf16, XOR-swizzled chunks by (col&7))
    int c = tid >> 1, half = tid & 1;
    const float* src = kvb + (size_t)head * 8192 + (c >> 6) * 4096 + (c & 63) * 64 + half * 32;
    float fv[32];
#pragma unroll
    for (int q = 0; q < 8; ++q) *(float4*)(fv + q*4) = *(const float4*)(src + q*4);
#pragma unroll
    for (int q2 = 0; q2 < 4; ++q2) {
      us8 o;
#pragma unroll
      for (int i = 0; i < 8; ++i) o[i] = f2bf(fv[q2*8 + i]);
      int chunk = half*4 + q2;
      *(us8*)((char*)Bl + c*128 + ((chunk ^ (c & 7)) << 4)) = o;
    }
    if (tid < 16) {
      int cc = 128 + (tid >> 3), q = tid & 7;
      const float* s2 = ksumb + head*128 + (tid >> 3)*64 + q*8;
      us8 o;
#pragma unroll
      for (int i = 0; i < 8; ++i) o[i] = f2bf(s2[i]);
      *(us8*)((char*)Bl + cc*128 + ((q ^ (cc & 7)) << 4)) = o;
    } else if (tid < 128) {
      int idx = tid - 16;
      int cc = 130 + (idx >> 3), q = idx & 7;
      us8 o = {0,0,0,0,0,0,0,0};
      *(us8*)((char*)Bl + cc*128 + ((q ^ (cc & 7)) << 4)) = o;
    }
  }
  __syncthreads();

  f32x4 acc[2][9] = {};
  bf16x8 af[2][2];
  const size_t qrow0 = (size_t)(b * LL + l0 + w * 32);
#pragma unroll
  for (int kk = 0; kk < 2; ++kk)
#pragma unroll
    for (int m = 0; m < 2; ++m)
      af[m][kk] = *(const bf16x8*)(qkv + (qrow0 + m*16 + lr) * E3 + h*64 + kk*32 + lg*8);
#pragma unroll
  for (int kk = 0; kk < 2; ++kk)
#pragma unroll
    for (int n = 0; n < 9; ++n) {
      int cc = n*16 + lr;
      bf16x8 bb = *(const bf16x8*)((const char*)Bl + cc*128 + ((((kk*4)+lg) ^ (cc & 7)) << 4));
#pragma unroll
      for (int m = 0; m < 2; ++m)
        acc[m][n] = __builtin_amdgcn_mfma_f32_16x16x32_bf16(af[m][kk], bb, acc[m][n], 0, 0, 0);
    }

  __syncthreads();   // Bl reads done; reuse as per-wave strips
  unsigned short* strip = (unsigned short*)Bl + w * 2048;   // [32][64] bf16
#pragma unroll
  for (int m = 0; m < 2; ++m)
#pragma unroll
    for (int j = 0; j < 4; ++j) {
      int rloc = m*16 + lg*4 + j;
      int pos = l0 + w*32 + rloc;
      float s_, c_;
      __sincosf((float)pos * ANGC, &s_, &c_);
      float nc = __shfl(acc[m][8][j], lane & 48, 64);          // col 128 (lr=0)
      float ns = __shfl(acc[m][8][j], (lane & 48) | 1, 64);    // col 129 (lr=1)
      float rn = 1.0f / (c_ * nc + s_ * ns + EPSC);
#pragma unroll
      for (int n = 0; n < 4; ++n) {
        float ctx = (c_ * acc[m][n][j] + s_ * acc[m][n+4][j]) * rn;
        strip[rloc*64 + n*16 + lr] = f2bf(ctx);
      }
    }
  __syncthreads();
#pragma unroll
  for (int p = 0; p < 4; ++p) {
    int ch = p*64 + lane;
    int row = ch >> 3, piece = ch & 7;
    us8 o = *(const us8*)(strip + row*64 + piece*8);
    *(us8*)(att + (size_t)(b*LL + l0 + w*32 + row) * EE + h*64 + piece*8) = o;
  }
}

// ---------------- launcher ----------------
extern "C" void kernel_launch(void* const* d_in, const int* in_sizes, int n_in,
                              void* d_out, int out_size, void* d_ws, size_t ws_size,
                              hipStream_t stream) {
  const float* x     = (const float*)d_in[0];
  const float* W_qkv = (const float*)d_in[1];
  const float* b_qkv = (const float*)d_in[2];
  const float* W_out = (const float*)d_in[3];
  const float* b_out = (const float*)d_in[4];

  char* w = (char*)d_ws;
  unsigned short* xb  = (unsigned short*)(w);                 // 33,554,432 B
  unsigned short* qkv = (unsigned short*)(w + 33554432);      // 100,663,296 B
  unsigned short* WqT = (unsigned short*)(w + 134217728);     // 6,291,456 B
  unsigned short* WoT = (unsigned short*)(w + 140509184);     // 2,097,152 B
  float* kvb   = (float*)(w + 142606336);                     // 2,097,152 B
  float* ksum  = (float*)(w + 144703488);                     // 32,768 B  (total 144,736,256)
  unsigned short* att = xb;   // reuse: x dead after GEMM1

  // k_prep blocks [12288,12808) zero kvb+ksum (520 x 4096 B = 2,129,920 B exactly)
  k_prep<<<12808, 256, 0, stream>>>(x, W_qkv, W_out, xb, WqT, WoT, kvb);
  k_gemm256<0><<<dim3(12, 64), 512, 0, stream>>>(xb, WqT, b_qkv, (void*)qkv, 3072, 1024);
  k_stage2<<<dim3(4, 64), 256, 0, stream>>>(qkv, kvb, ksum);
  k_stage3<<<dim3(32, 64), 256, 0, stream>>>(qkv, kvb, ksum, att);
  k_gemm256<1><<<dim3(4, 64), 512, 0, stream>>>(att, WoT, b_out, d_out, 1024, 1024);
}

// Round 14
// 202.418 us; speedup vs baseline: 1.0355x; 1.0355x over previous
//
#include <hip/hip_runtime.h>
#include <hip/hip_bf16.h>
#include <cstdint>
#include <cstddef>

// Problem constants
#define BB 4
#define LL 4096
#define HH 16
#define M1 16384      // B*L
#define E3 3072
#define EE 1024
#define ANGC 3.8349519697141029e-4f   // (pi/2)/4096
#define EPSC 1e-4f

typedef __attribute__((ext_vector_type(8))) short bf16x8;
typedef __attribute__((ext_vector_type(4))) float f32x4;
typedef __attribute__((ext_vector_type(8))) unsigned short us8;

static __device__ __forceinline__ float bf2f(unsigned short u) {
  union { unsigned int i; float f; } a; a.i = ((unsigned int)u) << 16; return a.f;
}
static __device__ __forceinline__ unsigned short f2bf(float x) {
  union { float f; unsigned int i; } a; a.f = x;
  unsigned int r = a.i + 0x7FFFu + ((a.i >> 16) & 1u);  // RNE
  return (unsigned short)(r >> 16);
}
static __device__ __forceinline__ void gload16(const void* g, void* l) {
  __builtin_amdgcn_global_load_lds((const __attribute__((address_space(1))) void*)g,
                                   (__attribute__((address_space(3))) void*)l, 16, 0, 0);
}

#define BAR()   asm volatile("s_barrier" ::: "memory")
#define VMC4()  asm volatile("s_waitcnt vmcnt(4)" ::: "memory")
#define VMC0()  asm volatile("s_waitcnt vmcnt(0)" ::: "memory")
#define PRIO1() __builtin_amdgcn_s_setprio(1)
#define PRIO0() __builtin_amdgcn_s_setprio(0)

// ---------------- fused prep: x f32->bf16 cvt + W transposes + kvb/ksum zero ----------------
static __device__ __forceinline__ void transpose_body(const float* __restrict__ src,
                                                      unsigned short* __restrict__ dst,
                                                      int R, int C, int bx, int by,
                                                      float (*tile)[33]) {
  int c0 = bx * 32, r0 = by * 32;
  int tx = threadIdx.x & 31, ty = threadIdx.x >> 5;
#pragma unroll
  for (int k = 0; k < 4; ++k)
    tile[ty + 8*k][tx] = src[(size_t)(r0 + ty + 8*k) * C + c0 + tx];
  __syncthreads();
#pragma unroll
  for (int k = 0; k < 4; ++k)
    dst[(size_t)(c0 + ty + 8*k) * R + r0 + tx] = f2bf(tile[tx][ty + 8*k]);
}

__global__ __launch_bounds__(256) void k_prep(const float* __restrict__ x,
                                              const float* __restrict__ Wq,
                                              const float* __restrict__ Wo,
                                              unsigned short* __restrict__ xb,
                                              unsigned short* __restrict__ WqT,
                                              unsigned short* __restrict__ WoT,
                                              float* __restrict__ zbase) {
  __shared__ float tile[32][33];
  const int bid = blockIdx.x;
  if (bid < 8192) {                       // cvt x: 8192*256 = 2097152 us8-chunks
    int i = bid * 256 + threadIdx.x;
    const float4* s = (const float4*)x + (size_t)i * 2;
    float4 a = s[0], b = s[1];
    us8 o;
    o[0]=f2bf(a.x); o[1]=f2bf(a.y); o[2]=f2bf(a.z); o[3]=f2bf(a.w);
    o[4]=f2bf(b.x); o[5]=f2bf(b.y); o[6]=f2bf(b.z); o[7]=f2bf(b.w);
    *(us8*)(xb + (size_t)i * 8) = o;
  } else if (bid < 8192 + 3072) {         // W_qkv transpose: 96 x 32 blocks
    int r = bid - 8192;
    transpose_body(Wq, WqT, 1024, 3072, r % 96, r / 96, tile);
  } else if (bid < 11264 + 1024) {        // W_out transpose: 32 x 32 blocks
    int r = bid - 11264;
    transpose_body(Wo, WoT, 1024, 1024, r % 32, r / 32, tile);
  } else {                                // zero kvb+ksum: 520 blocks x 4096B
    int r = bid - 12288;
    float4 z = {0.f, 0.f, 0.f, 0.f};
    *(float4*)((char*)zbase + (size_t)r * 4096 + threadIdx.x * 16) = z;
  }
}

// ============ 256x256 bf16 MFMA GEMM — 4-window schedule (R12 best-known, restored) ============
// C[M,N] = A[M,K] @ Bt[N,K]^T + bias.  MODE 0: bf16 out + relu cols<2048. MODE 1: f32 out.
// 512 thr = 8 waves (2M x 4N); per-wave 128x64 out = acc[8][4]; BK=64; LDS 128KB (2 bufs).
// LDS tile [256 rows][8 chunks of 16B], chunk-slot swizzle slot = ck ^ (row&7), applied
// BOTH sides (inverse-swizzled global source, swizzled ds_read).  K-loop conflict-free
// (786K SQ_LDS_BANK_CONFLICT = epilogue baseline).
// Schedule history: R13's m201-style double-barrier phases REGRESSED (38.9% MfmaUtil,
// +8 µs — 16 barriers/iter convergence cost at K=1024's 8 iterations); R11's 16-wave
// TLP REGRESSED (doubles LDS frag traffic); R6/R8 32x32 MFMA REGRESSED (layout/coalesce
// conflicts). This 4-window single-barrier form is the measured optimum (42.7% MfmaUtil,
// 959 TF). Remaining ~40%/iter is exposed latency/serialization; the path past it is
// AITER-style inline-asm 1:1 MFMA<->load interleave, not HIP-level scheduling.
//   W0-end: WAR barrier (LB0 fully read in W0 before W1 stages it)
//   W1-end: VMC4 gate (publishes t1.A + leftover t1.B) + WAR for LA0
//   W2-end: WAR barrier (LB1 read before W3 stages it)
//   W3-end: VMC4 gate (publishes t2.A + t2.B for next iter)
// Last iter: VMC0 at W1 gate (t1.A is newest outstanding).

static __device__ __forceinline__ bf16x8 rdfrag(const char* base, int row, int ck) {
  return *(const bf16x8*)(base + row * 128 + (((ck) ^ ((row) & 7)) << 4));
}

static __device__ __forceinline__ void stage2h(const unsigned short* __restrict__ base,
                                               size_t off, size_t rowK64, char* ldst) {
  gload16(base + off, ldst);
  gload16(base + off + rowK64, ldst + 8192);
}

#define PH_FIRST(AbP, BbP, AR)                                                  \
  do {                                                                          \
    _Pragma("unroll")                                                           \
    for (int n = 0; n < 4; ++n) {                                               \
      const int br = wc * 64 + n * 16 + lr;                                     \
      bF[n][0] = rdfrag((BbP), br, lg);                                         \
      bF[n][1] = rdfrag((BbP), br, 4 + lg);                                     \
    }                                                                           \
    AR[0][0] = rdfrag((AbP), wr * 128 + lr, lg);                                \
    AR[0][1] = rdfrag((AbP), wr * 128 + lr, 4 + lg);                            \
    AR[1][0] = rdfrag((AbP), wr * 128 + 16 + lr, lg);                           \
    AR[1][1] = rdfrag((AbP), wr * 128 + 16 + lr, 4 + lg);                       \
  } while (0)

#define PH_A(AbP, mb, AR)                                                       \
  do {                                                                          \
    AR[0][0] = rdfrag((AbP), wr * 128 + (mb) * 16 + lr, lg);                    \
    AR[0][1] = rdfrag((AbP), wr * 128 + (mb) * 16 + lr, 4 + lg);                \
    AR[1][0] = rdfrag((AbP), wr * 128 + (mb) * 16 + 16 + lr, lg);               \
    AR[1][1] = rdfrag((AbP), wr * 128 + (mb) * 16 + 16 + lr, 4 + lg);           \
  } while (0)

#define MMA16(mb, AR)                                                           \
  do {                                                                          \
    _Pragma("unroll")                                                           \
    for (int kk = 0; kk < 2; ++kk) {                                            \
      _Pragma("unroll")                                                         \
      for (int n = 0; n < 4; ++n) {                                             \
        acc[(mb)][n] = __builtin_amdgcn_mfma_f32_16x16x32_bf16(                 \
            AR[0][kk], bF[n][kk], acc[(mb)][n], 0, 0, 0);                       \
        acc[(mb) + 1][n] = __builtin_amdgcn_mfma_f32_16x16x32_bf16(             \
            AR[1][kk], bF[n][kk], acc[(mb) + 1][n], 0, 0, 0);                   \
      }                                                                         \
    }                                                                           \
  } while (0)

template<int MODE>
__global__ __launch_bounds__(512, 2) void k_gemm256(const unsigned short* __restrict__ A,
                                                    const unsigned short* __restrict__ Bt,
                                                    const float* __restrict__ bias,
                                                    void* __restrict__ Cout,
                                                    int N, int K) {
  __shared__ __align__(16) unsigned short lds[4][16384];  // [buf*2 + (0=A,1=B)][256 rows * 64]
  const int tid = threadIdx.x;
  const int wid = tid >> 6, lane = tid & 63;
  const int lr = lane & 15, lg = lane >> 4;
  const int wr = wid >> 2, wc = wid & 3;

  // L2 mapping: per-XCD 4x4 tile rectangles (working set 4 A + 4 B panels = 4MB L2 fit).
  // Bijective for G1 (nwg=768) and G2 (nwg=256).
  const int nx = gridDim.x;
  const int rawbid = blockIdx.y * nx + blockIdx.x;
  const int xcd = rawbid & 7, s = rawbid >> 3;
  const int g = s >> 4, r = s & 15;
  const int bm = (xcd * 8 + ((g & 1) << 2) + (r & 3)) * 256;
  const int bn = ((g >> 1) * 4 + (r >> 2)) * 256;

  char* LA0 = (char*)&lds[0][0];
  char* LB0 = (char*)&lds[1][0];
  char* LA1 = (char*)&lds[2][0];
  char* LB1 = (char*)&lds[3][0];

  f32x4 acc[8][4] = {};
  bf16x8 bF[4][2], aF[2][2], aG[2][2];

  // staging: thread covers rows {h*128+rr, +64}, stored chunk cc, src chunk cc^(rr&7)
  const int rr = tid >> 3, cc = tid & 7;
  const size_t rowK64 = (size_t)64 * K, rowK128 = (size_t)128 * K;
  const size_t aoff = (size_t)(bm + rr) * K + ((cc ^ (rr & 7)) << 3);
  const size_t boff = (size_t)(bn + rr) * K + ((cc ^ (rr & 7)) << 3);

#define STAGE_A(h, kt, L) stage2h(A,  aoff + (h) * rowK128 + (kt), rowK64, (L) + (h) * 16384 + tid * 16)
#define STAGE_B(h, kt, L) stage2h(Bt, boff + (h) * rowK128 + (kt), rowK64, (L) + (h) * 16384 + tid * 16)

  const int NT = K >> 6, NI = NT >> 1;

  // prologue: T0 full (buf0) + T1.B (buf1); VMC4 retires T0 (8 loads), leaves T1.B (4)
  STAGE_A(0, 0, LA0); STAGE_A(1, 0, LA0);
  STAGE_B(0, 0, LB0); STAGE_B(1, 0, LB0);
  STAGE_B(0, 64, LB1); STAGE_B(1, 64, LB1);
  VMC4();
  BAR();

  for (int it = 0; it < NI; ++it) {
    const int kt1 = (2*it + 1) << 6;
    const int kt2 = (2*it + 2) << 6;
    const int kt3 = (2*it + 3) << 6;
    const bool s2 = kt2 < K, s3 = kt3 < K;

    // ---- W0: tile t0, m0-3 ----
    PH_FIRST(LA0, LB0, aF);
    STAGE_A(0, kt1, LA1);
    PH_A(LA0, 2, aG);
    STAGE_A(1, kt1, LA1);
    PRIO1(); MMA16(0, aF); MMA16(2, aG); PRIO0();
    BAR();                                  // LB0 fully read -> W1 may stage it

    // ---- W1: tile t0, m4-7 ----
    PH_A(LA0, 4, aF);
    if (s2) STAGE_B(0, kt2, LB0);
    PH_A(LA0, 6, aG);
    if (s2) STAGE_B(1, kt2, LB0);
    PRIO1(); MMA16(4, aF); MMA16(6, aG); PRIO0();
    if (it == NI - 1) { VMC0(); } else { VMC4(); }   // gate: publish t1.A (+leftover t1.B)
    BAR();                                  // also: LA0 fully read -> W2 may stage it

    // ---- W2: tile t1, m0-3 ----
    PH_FIRST(LA1, LB1, aF);
    if (s2) STAGE_A(0, kt2, LA0);
    PH_A(LA1, 2, aG);
    if (s2) STAGE_A(1, kt2, LA0);
    PRIO1(); MMA16(0, aF); MMA16(2, aG); PRIO0();
    BAR();                                  // LB1 fully read -> W3 may stage it

    // ---- W3: tile t1, m4-7 ----
    PH_A(LA1, 4, aF);
    if (s3) STAGE_B(0, kt3, LB1);
    PH_A(LA1, 6, aG);
    if (s3) STAGE_B(1, kt3, LB1);
    PRIO1(); MMA16(4, aF); MMA16(6, aG); PRIO0();
    VMC4();                                 // gate: publish t2.A + t2.B for next iter
    BAR();
  }
#undef STAGE_A
#undef STAGE_B

  // ---------- epilogue: per-wave LDS strip transpose, coalesced stores ----------
  {
    float* strip = (float*)((char*)&lds[0][0] + wid * 16384);  // 16KB per wave, [16][68] f32
    float bias_v[4]; bool relu_v[4];
#pragma unroll
    for (int n = 0; n < 4; ++n) {
      int col = bn + wc*64 + n*16 + lr;
      bias_v[n] = bias[col];
      relu_v[n] = (MODE == 0) && (col < 2048);
    }
#pragma unroll
    for (int m = 0; m < 8; ++m) {
#pragma unroll
      for (int n = 0; n < 4; ++n)
#pragma unroll
        for (int j = 0; j < 4; ++j) {
          float v = acc[m][n][j] + bias_v[n];
          if (relu_v[n]) v = fmaxf(v, 0.0f);
          strip[(lg*4 + j)*68 + n*16 + lr] = v;
        }
      // wave-local RAW/WAR through LDS: compiler inserts lgkmcnt waits
#pragma unroll
      for (int itr = 0; itr < 4; ++itr) {
        int ch = itr*64 + lane;
        int row = ch >> 4, cg = ch & 15;
        float4 v = *(const float4*)(strip + row*68 + cg*4);
        size_t base = (size_t)(bm + wr*128 + m*16 + row) * N + bn + wc*64 + cg*4;
        if (MODE == 0) {
          ushort4 o;
          o.x = f2bf(v.x); o.y = f2bf(v.y); o.z = f2bf(v.z); o.w = f2bf(v.w);
          *(ushort4*)((unsigned short*)Cout + base) = o;
        } else {
          *(float4*)((float*)Cout + base) = v;
        }
      }
    }
  }
}

// ---------------- stage2: per-head KVc^T/KVs^T accumulation + k-sums ----------------
// Coalesced (R7) + low-contention (R9): grid (4, 64) = 256 blocks (1/CU), each block
// covers 1024 l in 16 subchunks of 64. Thread (pr=tid>>3, pc=tid&7) loads rows l0=2pr,
// l0+1 at d-piece pc*8..+7 — 8 lanes cover one row's 128B contiguously. LDS transpose
// via u32 writes. Swizzle S(d) = (d&7)^(d>>3), both sides.
static __device__ __forceinline__ int swz2(int d) { return (d & 7) ^ (d >> 3); }

__global__ __launch_bounds__(256) void k_stage2(const unsigned short* __restrict__ qkv,
                                                float* __restrict__ kvb,
                                                float* __restrict__ ksumb) {
  __shared__ __align__(16) unsigned short kcT[4096];
  __shared__ __align__(16) unsigned short ksT[4096];
  __shared__ __align__(16) unsigned short vT [4096];
  const int tid = threadIdx.x;
  const int head = blockIdx.y;
  const int b = head >> 4, h = head & 15;
  const int lane = tid & 63, wid = tid >> 6;
  const int lr = lane & 15, lg = lane >> 4;
  const int mt = wid >> 1, eh = wid & 1;
  const int pr = tid >> 3;        // l-pair index: l = 2pr, 2pr+1
  const int pc = tid & 7;         // d-piece: d = pc*8 + i

  f32x4 acc[2][4] = {};
  float ksacc = 0.0f;
  const int mtk = tid >> 6, dk = tid & 63;   // ksum role (tid<128)
  const size_t qbase = (size_t)b * LL * E3;

  for (int sc = 0; sc < 16; ++sc) {
    const int lbase = blockIdx.x * 1024 + sc * 64;
    __syncthreads();
    {
      const int l0 = 2 * pr;
      const int p0 = lbase + l0;
      float s0, c0, s1, c1;
      __sincosf((float)p0 * ANGC, &s0, &c0);
      __sincosf((float)(p0 + 1) * ANGC, &s1, &c1);
      const unsigned short* kp = qkv + qbase + (size_t)p0 * E3 + 1024 + h*64 + pc*8;
      us8 kr0 = *(const us8*)kp;
      us8 kr1 = *(const us8*)(kp + E3);
      us8 vr0 = *(const us8*)(kp + 1024);
      us8 vr1 = *(const us8*)(kp + 1024 + E3);
      const int cch = pr >> 2, wb = (pr & 3) * 4;
#pragma unroll
      for (int i = 0; i < 8; ++i) {
        int d = pc*8 + i;
        float ka = bf2f(kr0[i]), kb = bf2f(kr1[i]);
        unsigned int kcp = (unsigned int)f2bf(c0*ka) | ((unsigned int)f2bf(c1*kb) << 16);
        unsigned int ksp = (unsigned int)f2bf(s0*ka) | ((unsigned int)f2bf(s1*kb) << 16);
        unsigned int vp  = (unsigned int)vr0[i] | ((unsigned int)vr1[i] << 16);
        int off = d*128 + ((cch ^ swz2(d)) << 4) + wb;
        *(unsigned int*)((char*)kcT + off) = kcp;
        *(unsigned int*)((char*)ksT + off) = ksp;
        *(unsigned int*)((char*)vT  + off) = vp;
      }
    }
    __syncthreads();
    if (tid < 128) {   // k-sums: row-sum over l of kcT/ksT row dk
      const unsigned short* basep = mtk ? ksT : kcT;
      float sum = 0.0f;
#pragma unroll
      for (int cch2 = 0; cch2 < 8; ++cch2) {
        us8 r2 = *(const us8*)((const char*)basep + dk*128 + ((cch2 ^ swz2(dk)) << 4));
#pragma unroll
        for (int i = 0; i < 8; ++i) sum += bf2f(r2[i]);
      }
      ksacc += sum;
    }
    {
      const unsigned short* kT = mt ? ksT : kcT;
      bf16x8 af[2][2], bf[2][4];
#pragma unroll
      for (int kk = 0; kk < 2; ++kk) {
#pragma unroll
        for (int m = 0; m < 2; ++m) {
          int e = eh*32 + m*16 + lr;
          af[kk][m] = *(const bf16x8*)((const char*)vT + e*128 + ((((kk*4)+lg) ^ swz2(e)) << 4));
        }
#pragma unroll
        for (int n = 0; n < 4; ++n) {
          int d = n*16 + lr;
          bf[kk][n] = *(const bf16x8*)((const char*)kT + d*128 + ((((kk*4)+lg) ^ swz2(d)) << 4));
        }
      }
#pragma unroll
      for (int kk = 0; kk < 2; ++kk)
#pragma unroll
        for (int m = 0; m < 2; ++m)
#pragma unroll
          for (int n = 0; n < 4; ++n)
            acc[m][n] = __builtin_amdgcn_mfma_f32_16x16x32_bf16(af[kk][m], bf[kk][n], acc[m][n], 0, 0, 0);
    }
  }
  float* dst = kvb + (size_t)head * 8192 + mt * 4096;
#pragma unroll
  for (int m = 0; m < 2; ++m)
#pragma unroll
    for (int n = 0; n < 4; ++n)
#pragma unroll
      for (int j = 0; j < 4; ++j) {
        int e = eh*32 + m*16 + lg*4 + j;
        int d = n*16 + lr;
        atomicAdd(&dst[e*64 + d], acc[m][n][j]);
      }
  if (tid < 128) atomicAdd(&ksumb[head*128 + mtk*64 + dk], ksacc);
}

// ---------------- stage3: context + norm + divide -> att bf16 [B*L][E] ----------------
__global__ __launch_bounds__(256) void k_stage3(const unsigned short* __restrict__ qkv,
                                                const float* __restrict__ kvb,
                                                const float* __restrict__ ksumb,
                                                unsigned short* __restrict__ att) {
  __shared__ __align__(16) unsigned short Bl[144 * 64];   // 18KB; reused as strips
  const int tid = threadIdx.x;
  const int head = blockIdx.y;
  const int b = head >> 4, h = head & 15;
  const int l0 = blockIdx.x * 128;
  const int lane = tid & 63, w = tid >> 6;
  const int lr = lane & 15, lg = lane >> 4;

  { // load B into LDS (bf16, XOR-swizzled chunks by (col&7))
    int c = tid >> 1, half = tid & 1;
    const float* src = kvb + (size_t)head * 8192 + (c >> 6) * 4096 + (c & 63) * 64 + half * 32;
    float fv[32];
#pragma unroll
    for (int q = 0; q < 8; ++q) *(float4*)(fv + q*4) = *(const float4*)(src + q*4);
#pragma unroll
    for (int q2 = 0; q2 < 4; ++q2) {
      us8 o;
#pragma unroll
      for (int i = 0; i < 8; ++i) o[i] = f2bf(fv[q2*8 + i]);
      int chunk = half*4 + q2;
      *(us8*)((char*)Bl + c*128 + ((chunk ^ (c & 7)) << 4)) = o;
    }
    if (tid < 16) {
      int cc = 128 + (tid >> 3), q = tid & 7;
      const float* s2 = ksumb + head*128 + (tid >> 3)*64 + q*8;
      us8 o;
#pragma unroll
      for (int i = 0; i < 8; ++i) o[i] = f2bf(s2[i]);
      *(us8*)((char*)Bl + cc*128 + ((q ^ (cc & 7)) << 4)) = o;
    } else if (tid < 128) {
      int idx = tid - 16;
      int cc = 130 + (idx >> 3), q = idx & 7;
      us8 o = {0,0,0,0,0,0,0,0};
      *(us8*)((char*)Bl + cc*128 + ((q ^ (cc & 7)) << 4)) = o;
    }
  }
  __syncthreads();

  f32x4 acc[2][9] = {};
  bf16x8 af[2][2];
  const size_t qrow0 = (size_t)(b * LL + l0 + w * 32);
#pragma unroll
  for (int kk = 0; kk < 2; ++kk)
#pragma unroll
    for (int m = 0; m < 2; ++m)
      af[m][kk] = *(const bf16x8*)(qkv + (qrow0 + m*16 + lr) * E3 + h*64 + kk*32 + lg*8);
#pragma unroll
  for (int kk = 0; kk < 2; ++kk)
#pragma unroll
    for (int n = 0; n < 9; ++n) {
      int cc = n*16 + lr;
      bf16x8 bb = *(const bf16x8*)((const char*)Bl + cc*128 + ((((kk*4)+lg) ^ (cc & 7)) << 4));
#pragma unroll
      for (int m = 0; m < 2; ++m)
        acc[m][n] = __builtin_amdgcn_mfma_f32_16x16x32_bf16(af[m][kk], bb, acc[m][n], 0, 0, 0);
    }

  __syncthreads();   // Bl reads done; reuse as per-wave strips
  unsigned short* strip = (unsigned short*)Bl + w * 2048;   // [32][64] bf16
#pragma unroll
  for (int m = 0; m < 2; ++m)
#pragma unroll
    for (int j = 0; j < 4; ++j) {
      int rloc = m*16 + lg*4 + j;
      int pos = l0 + w*32 + rloc;
      float s_, c_;
      __sincosf((float)pos * ANGC, &s_, &c_);
      float nc = __shfl(acc[m][8][j], lane & 48, 64);          // col 128 (lr=0)
      float ns = __shfl(acc[m][8][j], (lane & 48) | 1, 64);    // col 129 (lr=1)
      float rn = 1.0f / (c_ * nc + s_ * ns + EPSC);
#pragma unroll
      for (int n = 0; n < 4; ++n) {
        float ctx = (c_ * acc[m][n][j] + s_ * acc[m][n+4][j]) * rn;
        strip[rloc*64 + n*16 + lr] = f2bf(ctx);
      }
    }
  __syncthreads();
#pragma unroll
  for (int p = 0; p < 4; ++p) {
    int ch = p*64 + lane;
    int row = ch >> 3, piece = ch & 7;
    us8 o = *(const us8*)(strip + row*64 + piece*8);
    *(us8*)(att + (size_t)(b*LL + l0 + w*32 + row) * EE + h*64 + piece*8) = o;
  }
}

// ---------------- launcher ----------------
extern "C" void kernel_launch(void* const* d_in, const int* in_sizes, int n_in,
                              void* d_out, int out_size, void* d_ws, size_t ws_size,
                              hipStream_t stream) {
  const float* x     = (const float*)d_in[0];
  const float* W_qkv = (const float*)d_in[1];
  const float* b_qkv = (const float*)d_in[2];
  const float* W_out = (const float*)d_in[3];
  const float* b_out = (const float*)d_in[4];

  char* w = (char*)d_ws;
  unsigned short* xb  = (unsigned short*)(w);                 // 33,554,432 B
  unsigned short* qkv = (unsigned short*)(w + 33554432);      // 100,663,296 B
  unsigned short* WqT = (unsigned short*)(w + 134217728);     // 6,291,456 B
  unsigned short* WoT = (unsigned short*)(w + 140509184);     // 2,097,152 B
  float* kvb   = (float*)(w + 142606336);                     // 2,097,152 B
  float* ksum  = (float*)(w + 144703488);                     // 32,768 B  (total 144,736,256)
  unsigned short* att = xb;   // reuse: x dead after GEMM1

  // k_prep blocks [12288,12808) zero kvb+ksum (520 x 4096 B = 2,129,920 B exactly)
  k_prep<<<12808, 256, 0, stream>>>(x, W_qkv, W_out, xb, WqT, WoT, kvb);
  k_gemm256<0><<<dim3(12, 64), 512, 0, stream>>>(xb, WqT, b_qkv, (void*)qkv, 3072, 1024);
  k_stage2<<<dim3(4, 64), 256, 0, stream>>>(qkv, kvb, ksum);
  k_stage3<<<dim3(32, 64), 256, 0, stream>>>(qkv, kvb, ksum, att);
  k_gemm256<1><<<dim3(4, 64), 512, 0, stream>>>(att, WoT, b_out, d_out, 1024, 1024);
}